// Round 12
// baseline (1750.489 us; speedup 1.0000x reference)
//
#include <hip/hip_runtime.h>
#include <hip/hip_bf16.h>
#include <math.h>

#define NPTS 2048
#define NB 16
#define KNN 20

typedef __attribute__((ext_vector_type(8))) short bf16x8;
typedef __attribute__((ext_vector_type(4))) float f32x4;

__device__ __forceinline__ float lrelu(float v) { return fmaxf(v, 0.2f * v); }

__device__ __forceinline__ unsigned short bf16r(float a) {
    __hip_bfloat16 h = __float2bfloat16(a);
    unsigned short u; __builtin_memcpy(&u, &h, 2); return u;
}
__device__ __forceinline__ float bf2f(unsigned short u) {
    unsigned v = (unsigned)u << 16; float f; __builtin_memcpy(&f, &v, 4); return f;
}

// split two floats into packed bf16 hi pair + packed bf16 lo (residual) pair
__device__ __forceinline__ void split2(float a, float b, unsigned& hp, unsigned& lp) {
    float2 f2; f2.x = a; f2.y = b;
    __hip_bfloat162 h2 = __float22bfloat162_rn(f2);
    unsigned hb; __builtin_memcpy(&hb, &h2, 4);
    float la = a - __uint_as_float(hb << 16);
    float lb = b - __uint_as_float(hb & 0xFFFF0000u);
    float2 l2; l2.x = la; l2.y = lb;
    __hip_bfloat162 k2 = __float22bfloat162_rn(l2);
    unsigned lb2; __builtin_memcpy(&lb2, &k2, 4);
    hp = hb; lp = lb2;
}

// ---- DPP full-wave (64 lane) max reduce, result broadcast via readlane ----
template<int CTRL, int RM>
__device__ __forceinline__ float dpp_fmax_step(float x) {
    int t = __builtin_amdgcn_update_dpp((int)0xFF800000, __float_as_int(x),
                                        CTRL, RM, 0xF, false);
    return fmaxf(x, __int_as_float(t));
}
__device__ __forceinline__ float wave_max_bcast(float x) {
    x = dpp_fmax_step<0x111, 0xF>(x);   // row_shr:1
    x = dpp_fmax_step<0x112, 0xF>(x);   // row_shr:2
    x = dpp_fmax_step<0x114, 0xF>(x);   // row_shr:4
    x = dpp_fmax_step<0x118, 0xF>(x);   // row_shr:8
    x = dpp_fmax_step<0x142, 0xA>(x);   // row_bcast15
    x = dpp_fmax_step<0x143, 0xC>(x);   // row_bcast31 -> lane63 = all
    return __int_as_float(__builtin_amdgcn_readlane(__float_as_int(x), 63));
}

// ---- transpose x [B,N,3] -> h0 [B,3,N]
__global__ void transpose_kernel(const float* __restrict__ x, float* __restrict__ h0) {
    int t = blockIdx.x * blockDim.x + threadIdx.x;   // b*N+n
    if (t >= NB * NPTS) return;
    int b = t / NPTS, n = t % NPTS;
    const float* src = x + (size_t)t * 3;
    float* dst = h0 + (size_t)b * 3 * NPTS + n;
    dst[0]        = src[0];
    dst[NPTS]     = src[1];
    dst[2 * NPTS] = src[2];
}

// ---- fused: split fp32 [C][N] -> xs[b][n][3][CP] bf16 hi/mid/lo (zero-pad c>=C)
//      AND sq[b,n] = sum_c x^2 with the exact ascending-c fmaf chain.
template<int C, int CP>
__global__ __launch_bounds__(256) void split_sq_kernel(const float* __restrict__ in, long bstride,
                                                       unsigned short* __restrict__ xs,
                                                       float* __restrict__ sq) {
    int t = blockIdx.x * 256 + threadIdx.x;   // b*N+n
    int b = t >> 11, n = t & 2047;
    const float* p = in + (size_t)b * bstride + n;
    unsigned short* o = xs + (size_t)t * 3 * CP;
    float s = 0.f;
    for (int c0 = 0; c0 < CP; c0 += 4) {
        unsigned short hh[4], mm[4], ll[4];
#pragma unroll
        for (int i = 0; i < 4; ++i) {
            int c = c0 + i;
            float a = (c < C) ? p[(size_t)c * NPTS] : 0.f;
            if (c < C) s = fmaf(a, a, s);
            unsigned short h = bf16r(a);
            float r1 = a - bf2f(h);
            unsigned short m = bf16r(r1);
            float r2 = r1 - bf2f(m);
            unsigned short l = bf16r(r2);
            hh[i] = h; mm[i] = m; ll[i] = l;
        }
        *(uint2*)(o + 0 * CP + c0) = make_uint2((unsigned)hh[0] | ((unsigned)hh[1] << 16),
                                                (unsigned)hh[2] | ((unsigned)hh[3] << 16));
        *(uint2*)(o + 1 * CP + c0) = make_uint2((unsigned)mm[0] | ((unsigned)mm[1] << 16),
                                                (unsigned)mm[2] | ((unsigned)mm[3] << 16));
        *(uint2*)(o + 2 * CP + c0) = make_uint2((unsigned)ll[0] | ((unsigned)ll[1] << 16),
                                                (unsigned)ll[2] | ((unsigned)ll[3] << 16));
    }
    sq[t] = s;
}

// ---- kNN via MFMA bf16x3 distances (R6-passing kernel; ONLY change: 1D grid with
// b = id&15 XCD colocation so each XCD's L2 holds its 2 batches' xs slab (3MB<4MB)
// -> B-fragment loads become L2 hits instead of ~900cy HBM misses; R6's MfmaUtil 9%
// was exactly the HBM-latency duty cycle).
// Block: 16 query rows, 512 thr (8 waves). Two 1024-col halves into 64KB LDS.
// dist phys addr: p(lc,r) = r*1024 + (((lc ^ ((lc>>5&7)<<2)) + 4r) & 1023)
// Selection: per half, per row (wave w owns rows w, w+8): 16 cands/lane, 2 groups of 8,
// DPP wave-max + ballot-ctz extraction (smallest-index ties exact), 20 extractions;
// then exact A/B merge: A-top20 in lanes 0..19, B-top20 in lanes 32..51.
template<int CP>
__global__ __launch_bounds__(512) void knn_mfma_kernel(const unsigned short* __restrict__ xs,
                                                       const float* __restrict__ sq,
                                                       int* __restrict__ idxT) {
    __shared__ __align__(16) float dist[16 * 1024];   // 64KB
    constexpr int KC = CP / 32;
    int b = blockIdx.x & 15;
    int n0 = (blockIdx.x >> 4) * 16;
    int tid = threadIdx.x, lane = tid & 63, w = tid >> 6;
    int l15 = lane & 15, q = lane >> 4;

    // preload A fragments (the 16 query rows), reused for both halves
    bf16x8 af[KC][3];
    {
        const unsigned short* ab = xs + ((size_t)b * NPTS + n0 + l15) * 3 * CP + q * 8;
#pragma unroll
        for (int kc = 0; kc < KC; ++kc)
#pragma unroll
            for (int cp = 0; cp < 3; ++cp)
                af[kc][cp] = *(const bf16x8*)(ab + (size_t)cp * CP + kc * 32);
    }
    const float* sqb = sq + (size_t)b * NPTS;

    float avalr[2]; int aidxr[2];
    avalr[0] = avalr[1] = 0.f; aidxr[0] = aidxr[1] = 0;

    for (int half = 0; half < 2; ++half) {
        int chalf = half * 1024;
        int lcb0 = w * 128;
#pragma unroll 2
        for (int t8 = 0; t8 < 8; ++t8) {
            int lcb = lcb0 + t8 * 16;
            int gc = chalf + lcb + l15;
            const unsigned short* bb = xs + ((size_t)b * NPTS + gc) * 3 * CP + q * 8;
            f32x4 acc = (f32x4)0.f;
#pragma unroll
            for (int kc = 0; kc < KC; ++kc) {
                bf16x8 bh = *(const bf16x8*)(bb + 0 * CP + kc * 32);
                bf16x8 bm = *(const bf16x8*)(bb + 1 * CP + kc * 32);
                bf16x8 bl = *(const bf16x8*)(bb + 2 * CP + kc * 32);
                // low-order first: mm, hl, lh, hm, mh, hh
                acc = __builtin_amdgcn_mfma_f32_16x16x32_bf16(af[kc][1], bm, acc, 0, 0, 0);
                acc = __builtin_amdgcn_mfma_f32_16x16x32_bf16(af[kc][0], bl, acc, 0, 0, 0);
                acc = __builtin_amdgcn_mfma_f32_16x16x32_bf16(af[kc][2], bh, acc, 0, 0, 0);
                acc = __builtin_amdgcn_mfma_f32_16x16x32_bf16(af[kc][0], bm, acc, 0, 0, 0);
                acc = __builtin_amdgcn_mfma_f32_16x16x32_bf16(af[kc][1], bh, acc, 0, 0, 0);
                acc = __builtin_amdgcn_mfma_f32_16x16x32_bf16(af[kc][0], bh, acc, 0, 0, 0);
            }
            float sv = sqb[gc];
            int lc = lcb + l15;
            int pc = lc ^ (((lc >> 5) & 7) << 2);
#pragma unroll
            for (int j = 0; j < 4; ++j) {
                int r = q * 4 + j;
                dist[r * 1024 + ((pc + 4 * r) & 1023)] = 2.f * acc[j] - sv;
            }
        }
        __syncthreads();

        int swl = ((lane >> 1) & 7) << 2;
        for (int rs = 0; rs < 2; ++rs) {
            int r = w + 8 * rs;
            float v[16];
#pragma unroll
            for (int u = 0; u < 4; ++u) {
                int lcl = (16 * lane + 4 * u) ^ swl;
                const float4 tv = *(const float4*)&dist[r * 1024 + ((lcl + 4 * r) & 1023)];
                v[4 * u + 0] = tv.x; v[4 * u + 1] = tv.y;
                v[4 * u + 2] = tv.z; v[4 * u + 3] = tv.w;
            }
            float gm0 = v[0]; int gi0 = 0;
            float gm1 = v[8]; int gi1 = 8;
#pragma unroll
            for (int i = 1; i < 8; ++i) {
                if (v[i] > gm0) { gm0 = v[i]; gi0 = i; }
                if (v[8 + i] > gm1) { gm1 = v[8 + i]; gi1 = 8 + i; }
            }
            float lv = gm0; int lm = gi0;
            if (gm1 > lv) { lv = gm1; lm = gi1; }

            float cv = -INFINITY; int ci = 0;
            for (int j = 0; j < KNN; ++j) {
                float gv = wave_max_bcast(lv);
                unsigned long long mk = __ballot(lv == gv);
                int winner = (int)__builtin_ctzll(mk);
                int wm = __builtin_amdgcn_readlane(lm, winner);  // uniform slot 0..15
                int bm = chalf + winner * 16 + wm;
                cv = (lane == j) ? gv : cv;
                ci = (lane == j) ? bm : ci;
                bool iswin = (lane == winner);
                if ((wm >> 3) == 0) {            // uniform branch
#pragma unroll
                    for (int i = 0; i < 8; ++i)
                        v[i] = (iswin && (wm == i)) ? -INFINITY : v[i];
                    float nm = v[0]; int ni = 0;
#pragma unroll
                    for (int i = 1; i < 8; ++i) if (v[i] > nm) { nm = v[i]; ni = i; }
                    gm0 = iswin ? nm : gm0;
                    gi0 = iswin ? ni : gi0;
                } else {
#pragma unroll
                    for (int i = 8; i < 16; ++i)
                        v[i] = (iswin && (wm == i)) ? -INFINITY : v[i];
                    float nm = v[8]; int ni = 8;
#pragma unroll
                    for (int i = 9; i < 16; ++i) if (v[i] > nm) { nm = v[i]; ni = i; }
                    gm1 = iswin ? nm : gm1;
                    gi1 = iswin ? ni : gi1;
                }
                lv = gm0; lm = gi0;
                if (gm1 > lv) { lv = gm1; lm = gi1; }
            }

            if (half == 0) { avalr[rs] = cv; aidxr[rs] = ci; }
            else {
                // merge A-top20 (lanes 0..19) with B-top20 (shifted to lanes 32..51)
                int src = (lane >= 32) ? (lane - 32) : 0;
                float bsv = __shfl(cv, src, 64);
                int   bsi = __shfl(ci, src, 64);
                float mv; int mi2;
                if (lane < 20)                    { mv = avalr[rs]; mi2 = aidxr[rs]; }
                else if (lane >= 32 && lane < 52) { mv = bsv;       mi2 = bsi; }
                else                              { mv = -INFINITY; mi2 = 0; }
                int rbm = 0;
                for (int j = 0; j < KNN; ++j) {
                    float gv = wave_max_bcast(mv);
                    unsigned long long mk = __ballot(mv == gv);
                    int winner = (int)__builtin_ctzll(mk);
                    int widx = __builtin_amdgcn_readlane(mi2, winner);
                    rbm = (lane == j) ? widx : rbm;
                    mv = (lane == winner) ? -INFINITY : mv;
                }
                if (lane < KNN) idxT[((size_t)b * KNN + lane) * NPTS + n0 + r] = rbm;
            }
        }
        if (half == 0) __syncthreads();
    }
}

// ---- Wa[c][o] = W[o][c]; Wd[c][o] = W[o][C+c] - W[o][c]
__global__ void prep_w_kernel(const float* __restrict__ W, int C, int O,
                              float* __restrict__ Wa, float* __restrict__ Wd) {
    int t = blockIdx.x * blockDim.x + threadIdx.x;
    if (t >= C * O) return;
    int c = t / O, o = t % O;
    float a = W[o * 2 * C + c];
    float d = W[o * 2 * C + C + c] - a;
    Wa[c * O + o] = a;
    Wd[c * O + o] = d;
}

// ---- y[b,o,m] = Wa@x_m ; base[b,off+o,n] = Wd@x_n + bias
__global__ __launch_bounds__(256) void edge_mm_kernel(const float* __restrict__ xin, long bstride,
                                                      int C, int O,
                                                      const float* __restrict__ Wa,
                                                      const float* __restrict__ Wd,
                                                      const float* __restrict__ bias,
                                                      float* __restrict__ y,
                                                      float* __restrict__ base, long base_bstride) {
    int m = blockIdx.x * 256 + threadIdx.x;
    int ngrp = O >> 3;
    int og = blockIdx.y % ngrp, b = blockIdx.y / ngrp;
    int o0 = og * 8;
    const float* xb = xin + (size_t)b * bstride + m;
    float a1[8], a2[8];
#pragma unroll
    for (int i = 0; i < 8; ++i) { a1[i] = 0.f; a2[i] = 0.f; }
#pragma unroll 2
    for (int c = 0; c < C; ++c) {
        float h = xb[(size_t)c * NPTS];
        const float* wa = Wa + c * O + o0;
        const float* wd = Wd + c * O + o0;
#pragma unroll
        for (int i = 0; i < 8; ++i) {
            a1[i] = fmaf(wa[i], h, a1[i]);
            a2[i] = fmaf(wd[i], h, a2[i]);
        }
    }
#pragma unroll
    for (int i = 0; i < 8; ++i) {
        y[((size_t)b * O + o0 + i) * NPTS + m] = a1[i];
        base[(size_t)b * base_bstride + (size_t)(o0 + i) * NPTS + m] = a2[i] + bias[o0 + i];
    }
}

// ---- feat[b,o0+i,n] = lrelu( max_j y[b,o0+i,idxT[b,j,n]] + base ), 8 channels/block.
// Grid 1D = (O/8)*2*NB: b = id&15 (XCD colocation), nc = (id>>4)&1, og = id>>5.
__global__ __launch_bounds__(256) void gather_max_kernel(const float* __restrict__ y, int O,
                                                         const int* __restrict__ idxT,
                                                         float* __restrict__ feat_slice,
                                                         long bstride) {
    __shared__ __align__(16) float yrow[8][NPTS];   // 64 KB
    int b  = blockIdx.x & 15;
    int nc = (blockIdx.x >> 4) & 1;
    int og = blockIdx.x >> 5;
    int o0 = og * 8;
    const float* ysrc = y + ((size_t)b * O + o0) * NPTS;
    for (int e = threadIdx.x; e < 8 * (NPTS / 4); e += 256) {
        int i = e >> 9;
        int m4 = e & 511;
        *reinterpret_cast<float4*>(&yrow[i][4 * m4]) =
            *reinterpret_cast<const float4*>(&ysrc[(size_t)i * NPTS + 4 * m4]);
    }
    __syncthreads();
    float* fs = feat_slice + (size_t)b * bstride + (size_t)o0 * NPTS;
    const int* ib = idxT + (size_t)b * KNN * NPTS + nc * (NPTS / 2);
    for (int s = 0; s < 4; ++s) {
        int n = threadIdx.x + 256 * s;
        int gn = nc * (NPTS / 2) + n;
        float mx[8];
#pragma unroll
        for (int i = 0; i < 8; ++i) mx[i] = -INFINITY;
#pragma unroll 4
        for (int j = 0; j < KNN; ++j) {
            int id = ib[(size_t)j * NPTS + n];
#pragma unroll
            for (int i = 0; i < 8; ++i) mx[i] = fmaxf(mx[i], yrow[i][id]);
        }
#pragma unroll
        for (int i = 0; i < 8; ++i) {
            float* fp = fs + (size_t)i * NPTS + gn;
            *fp = lrelu(mx[i] + *fp);
        }
    }
}

// ---- split Wf (fp32 [1024][512]) into packed bf16 hi/lo
__global__ void wf_split_kernel(const float* __restrict__ Wf,
                                unsigned* __restrict__ Wfh, unsigned* __restrict__ Wfl) {
    int t = blockIdx.x * 256 + threadIdx.x;   // pair index
    if (t >= 262144) return;
    unsigned h, l;
    split2(Wf[2 * t], Wf[2 * t + 1], h, l);
    Wfh[t] = h; Wfl[t] = l;
}

// ---- final GEMM via bf16 hi/lo split MFMA, with max-over-n epilogue
#define GP 40   // LDS pitch in bf16 elements (+8 pad: 2-way bank aliasing only)
__global__ __launch_bounds__(256) void final_gemm_mfma(
    const float* __restrict__ feat,
    const unsigned short* __restrict__ Wfh,
    const unsigned short* __restrict__ Wfl,
    float* __restrict__ pmax) {
    __shared__ __align__(16) unsigned short Ah[128 * GP];
    __shared__ __align__(16) unsigned short Al[128 * GP];
    __shared__ __align__(16) unsigned short Bh[128 * GP];
    __shared__ __align__(16) unsigned short Bl[128 * GP];

    int ot = blockIdx.x, nt = blockIdx.y, b = blockIdx.z;
    int o0 = ot * 128, n0 = nt * 128;
    int tid = threadIdx.x;
    int lane = tid & 63, w = tid >> 6;
    int wm = w & 1, wn = w >> 1;
    int l15 = lane & 15, q = lane >> 4;

    f32x4 acc[4][4];
#pragma unroll
    for (int mi = 0; mi < 4; ++mi)
#pragma unroll
        for (int ni = 0; ni < 4; ++ni) acc[mi][ni] = (f32x4)0.f;

    const float* fb = feat + (size_t)b * 512 * NPTS;
    int bn = tid & 127, kh = tid >> 7;

    for (int c0 = 0; c0 < 512; c0 += 32) {
#pragma unroll
        for (int p = 0; p < 2; ++p) {
            int e = p * 256 + tid;
            int r = e >> 2, qq = e & 3;
            size_t go = (size_t)(o0 + r) * 512 + c0 + qq * 8;
            *(uint4*)&Ah[r * GP + qq * 8] = *(const uint4*)(Wfh + go);
            *(uint4*)&Al[r * GP + qq * 8] = *(const uint4*)(Wfl + go);
        }
        {
            const float* src = fb + (size_t)(c0 + kh * 16) * NPTS + n0 + bn;
            float v[16];
#pragma unroll
            for (int j = 0; j < 16; ++j) v[j] = src[(size_t)j * NPTS];
            unsigned hw[8], lw[8];
#pragma unroll
            for (int p = 0; p < 8; ++p) split2(v[2 * p], v[2 * p + 1], hw[p], lw[p]);
            unsigned short* bh = &Bh[bn * GP + kh * 16];
            unsigned short* bl = &Bl[bn * GP + kh * 16];
            *(uint4*)(bh)     = make_uint4(hw[0], hw[1], hw[2], hw[3]);
            *(uint4*)(bh + 8) = make_uint4(hw[4], hw[5], hw[6], hw[7]);
            *(uint4*)(bl)     = make_uint4(lw[0], lw[1], lw[2], lw[3]);
            *(uint4*)(bl + 8) = make_uint4(lw[4], lw[5], lw[6], lw[7]);
        }
        __syncthreads();

        bf16x8 bhf[4], blf[4];
#pragma unroll
        for (int ni = 0; ni < 4; ++ni) {
            int row = wn * 64 + ni * 16 + l15;
            bhf[ni] = *(const bf16x8*)&Bh[row * GP + q * 8];
            blf[ni] = *(const bf16x8*)&Bl[row * GP + q * 8];
        }
#pragma unroll
        for (int mi = 0; mi < 4; ++mi) {
            int row = wm * 64 + mi * 16 + l15;
            bf16x8 ah = *(const bf16x8*)&Ah[row * GP + q * 8];
            bf16x8 al = *(const bf16x8*)&Al[row * GP + q * 8];
#pragma unroll
            for (int ni = 0; ni < 4; ++ni) {
                acc[mi][ni] = __builtin_amdgcn_mfma_f32_16x16x32_bf16(ah, bhf[ni], acc[mi][ni], 0, 0, 0);
                acc[mi][ni] = __builtin_amdgcn_mfma_f32_16x16x32_bf16(ah, blf[ni], acc[mi][ni], 0, 0, 0);
                acc[mi][ni] = __builtin_amdgcn_mfma_f32_16x16x32_bf16(al, bhf[ni], acc[mi][ni], 0, 0, 0);
            }
        }
        __syncthreads();
    }

    int slot = nt * 2 + wn;
#pragma unroll
    for (int mi = 0; mi < 4; ++mi) {
        float m4[4];
#pragma unroll
        for (int r = 0; r < 4; ++r) {
            float m = acc[mi][0][r];
            m = fmaxf(m, acc[mi][1][r]);
            m = fmaxf(m, acc[mi][2][r]);
            m = fmaxf(m, acc[mi][3][r]);
            m4[r] = m;
        }
#pragma unroll
        for (int off = 1; off < 16; off <<= 1) {
#pragma unroll
            for (int r = 0; r < 4; ++r)
                m4[r] = fmaxf(m4[r], __shfl_xor(m4[r], off, 16));
        }
        if (l15 == 0) {
            int mbase = o0 + wm * 64 + mi * 16 + q * 4;
#pragma unroll
            for (int r = 0; r < 4; ++r)
                pmax[((size_t)b * 1024 + mbase + r) * 32 + slot] = m4[r];
        }
    }
}

__global__ void final_reduce_kernel(const float* __restrict__ pmax,
                                    const float* __restrict__ bf,
                                    float* __restrict__ out) {
    int t = blockIdx.x * blockDim.x + threadIdx.x;   // b*1024+o
    if (t >= NB * 1024) return;
    const float* p = pmax + (size_t)t * 32;
    float m = p[0];
#pragma unroll
    for (int i = 1; i < 32; ++i) m = fmaxf(m, p[i]);
    out[t] = lrelu(m + bf[t & 1023]);
}

extern "C" void kernel_launch(void* const* d_in, const int* in_sizes, int n_in,
                              void* d_out, int out_size, void* d_ws, size_t ws_size,
                              hipStream_t stream) {
    const float* x  = (const float*)d_in[0];
    const float* W[4]  = {(const float*)d_in[1], (const float*)d_in[3],
                          (const float*)d_in[5], (const float*)d_in[7]};
    const float* bb[4] = {(const float*)d_in[2], (const float*)d_in[4],
                          (const float*)d_in[6], (const float*)d_in[8]};
    const float* Wf = (const float*)d_in[9];
    const float* bf = (const float*)d_in[10];
    float* out = (float*)d_out;

    float* ws   = (float*)d_ws;
    float* h0   = ws;                           // B*3*N      = 98304
    float* sq   = ws + 98304;                   // B*N        = 32768
    int*   idxT = (int*)(sq + 32768);           // B*20*N     = 655360 (transposed [b][j][n])
    float* y    = (float*)(idxT + 655360);      // B*256*N    = 8388608 (reused)
    float* feat = y + 8388608;                  // B*512*N    = 16777216
    float* Wa   = feat + 16777216 + 262144;     // 128*256    = 32768
    float* Wd   = Wa + 32768;                   // 128*256    = 32768

    // xs (bf16 hi/mid/lo split, [b][n][3][CP]) lives in the y region; dead before edge_mm.
    unsigned short* xs = (unsigned short*)y;    // max 16*2048*3*128*2B = 25.2MB < 32MB

    // carved out of the dead y-region after layer 4:
    unsigned* Wfh = (unsigned*)y;                    // 262144 dwords
    unsigned* Wfl = (unsigned*)(y + 262144);         // 262144 dwords
    float*    pmax = y + 524288;                     // 16*1024*32 = 524288 floats

    transpose_kernel<<<128, 256, 0, stream>>>(x, h0);

    const int  Cs[4]   = {3, 64, 64, 128};
    const int  Os[4]   = {64, 64, 128, 256};
    const int  offs[4] = {0, 64, 128, 256};

    for (int l = 0; l < 4; ++l) {
        const float* in = (l == 0) ? h0 : feat + (size_t)offs[l - 1] * NPTS;
        long bstr = (l == 0) ? (long)3 * NPTS : (long)512 * NPTS;
        int C = Cs[l], O = Os[l];

        // 1D grid: 128 query-groups x 16 batches; b = id&15 -> XCD = b%8 colocation
        int kb = (NPTS / 16) * NB;   // 2048 blocks
        if (C == 3) {
            split_sq_kernel<3, 32><<<128, 256, 0, stream>>>(in, bstr, xs, sq);
            knn_mfma_kernel<32><<<kb, 512, 0, stream>>>(xs, sq, idxT);
        } else if (C == 64) {
            split_sq_kernel<64, 64><<<128, 256, 0, stream>>>(in, bstr, xs, sq);
            knn_mfma_kernel<64><<<kb, 512, 0, stream>>>(xs, sq, idxT);
        } else {
            split_sq_kernel<128, 128><<<128, 256, 0, stream>>>(in, bstr, xs, sq);
            knn_mfma_kernel<128><<<kb, 512, 0, stream>>>(xs, sq, idxT);
        }

        prep_w_kernel<<<(C * O + 255) / 256, 256, 0, stream>>>(W[l], C, O, Wa, Wd);

        float* fslice = feat + (size_t)offs[l] * NPTS;
        edge_mm_kernel<<<dim3(NPTS / 256, NB * (O >> 3)), 256, 0, stream>>>(
            in, bstr, C, O, Wa, Wd, bb[l], y, fslice, (long)512 * NPTS);

        // 1D grid: (O/8) o-groups x 2 n-halves x 16 batches; b = id&15 colocation
        gather_max_kernel<<<(O / 8) * 2 * NB, 256, 0, stream>>>(
            y, O, idxT, fslice, (long)512 * NPTS);
    }

    wf_split_kernel<<<1024, 256, 0, stream>>>(Wf, Wfh, Wfl);
    final_gemm_mfma<<<dim3(8, 16, NB), 256, 0, stream>>>(
        feat, (const unsigned short*)Wfh, (const unsigned short*)Wfl, pmax);
    final_reduce_kernel<<<64, 256, 0, stream>>>(pmax, bf, out);
}

// Round 13
// 1100.938 us; speedup vs baseline: 1.5900x; 1.5900x over previous
//
#include <hip/hip_runtime.h>
#include <hip/hip_bf16.h>
#include <math.h>

#define NPTS 2048
#define NB 16
#define KNN 20

typedef __attribute__((ext_vector_type(8))) short bf16x8;
typedef __attribute__((ext_vector_type(4))) float f32x4;

__device__ __forceinline__ float lrelu(float v) { return fmaxf(v, 0.2f * v); }

// split two floats into packed bf16 hi pair + packed bf16 lo (residual) pair
__device__ __forceinline__ void split2(float a, float b, unsigned& hp, unsigned& lp) {
    float2 f2; f2.x = a; f2.y = b;
    __hip_bfloat162 h2 = __float22bfloat162_rn(f2);
    unsigned hb; __builtin_memcpy(&hb, &h2, 4);
    float la = a - __uint_as_float(hb << 16);
    float lb = b - __uint_as_float(hb & 0xFFFF0000u);
    float2 l2; l2.x = la; l2.y = lb;
    __hip_bfloat162 k2 = __float22bfloat162_rn(l2);
    unsigned lb2; __builtin_memcpy(&lb2, &k2, 4);
    hp = hb; lp = lb2;
}

// ---- DPP full-wave (64 lane) max reduce, result broadcast via readlane ----
template<int CTRL, int RM>
__device__ __forceinline__ float dpp_fmax_step(float x) {
    int t = __builtin_amdgcn_update_dpp((int)0xFF800000, __float_as_int(x),
                                        CTRL, RM, 0xF, false);
    return fmaxf(x, __int_as_float(t));
}
__device__ __forceinline__ float wave_max_bcast(float x) {
    x = dpp_fmax_step<0x111, 0xF>(x);   // row_shr:1
    x = dpp_fmax_step<0x112, 0xF>(x);   // row_shr:2
    x = dpp_fmax_step<0x114, 0xF>(x);   // row_shr:4
    x = dpp_fmax_step<0x118, 0xF>(x);   // row_shr:8
    x = dpp_fmax_step<0x142, 0xA>(x);   // row_bcast15
    x = dpp_fmax_step<0x143, 0xC>(x);   // row_bcast31 -> lane63 = all
    return __int_as_float(__builtin_amdgcn_readlane(__float_as_int(x), 63));
}

// ---- transpose x [B,N,3] -> h0 [B,3,N]
__global__ void transpose_kernel(const float* __restrict__ x, float* __restrict__ h0) {
    int t = blockIdx.x * blockDim.x + threadIdx.x;   // b*N+n
    if (t >= NB * NPTS) return;
    int b = t / NPTS, n = t % NPTS;
    const float* src = x + (size_t)t * 3;
    float* dst = h0 + (size_t)b * 3 * NPTS + n;
    dst[0]        = src[0];
    dst[NPTS]     = src[1];
    dst[2 * NPTS] = src[2];
}

// ---- kNN (R11-proven numerics; ONLY change: __launch_bounds__(512, 2)).
// Previous builds compiled at VGPR_Count=52, spilling the v[32] selection array
// to scratch — scratch round-trips inside the serial 20-extraction chain made
// knn C-independent at ~300us (WRITE_SIZE 6.4MB vs 2.6MB of real output).
// (512,2) raises the register cap (>=128) while occupancy stays LDS-limited
// at 2 blocks/CU, so v[32]+acc[8] fit in registers. No code-path change.
// 1D grid 1024 blocks: b = id&15, qb = id>>4  ->  XCD = b%8 colocation.
// sn computed once (rg=0, ascending-c fmaf chain -> bit-identical dist).
// Selection: contiguous per-lane layout + XOR swizzle, DPP wave max, ballot+ctz
// (smallest-index ties), grouped (4x8) removal/rescan. Output idxT[b][j][n].
template<int C>
__global__ __launch_bounds__(512, 2) void knn_kernel(const float* __restrict__ xin, long bstride,
                                                     int* __restrict__ idxT) {
    __shared__ __align__(16) float dist[8][NPTS];   // 64 KB
    int b  = blockIdx.x & 15;
    int qb = blockIdx.x >> 4;
    int tid = threadIdx.x;
    int lane = tid & 63, w = tid >> 6;
    const float* xb = xin + (size_t)b * bstride;
    int m0 = 4 * tid;
    float4 sn = make_float4(0.f, 0.f, 0.f, 0.f);    // persists across groups

    for (int rg = 0; rg < 4; ++rg) {
        int n0 = qb * 32 + rg * 8;
        const float* xq = xb + n0;          // query columns base (lane-uniform)

        // ---- compute phase: thread owns columns m0..m0+3
        float4 acc[8];
#pragma unroll
        for (int r = 0; r < 8; ++r) acc[r] = make_float4(0.f, 0.f, 0.f, 0.f);

        if (rg == 0) {
#pragma unroll 4
            for (int c = 0; c < C; ++c) {
                const float* rowc = xb + (size_t)c * NPTS;
                float4 xv = *reinterpret_cast<const float4*>(&rowc[m0]);
                float4 q0 = *reinterpret_cast<const float4*>(&xq[(size_t)c * NPTS]);
                float4 q1 = *reinterpret_cast<const float4*>(&xq[(size_t)c * NPTS + 4]);
                sn.x = fmaf(xv.x, xv.x, sn.x);
                sn.y = fmaf(xv.y, xv.y, sn.y);
                sn.z = fmaf(xv.z, xv.z, sn.z);
                sn.w = fmaf(xv.w, xv.w, sn.w);
                float q[8] = {q0.x, q0.y, q0.z, q0.w, q1.x, q1.y, q1.z, q1.w};
#pragma unroll
                for (int r = 0; r < 8; ++r) {
                    acc[r].x = fmaf(q[r], xv.x, acc[r].x);
                    acc[r].y = fmaf(q[r], xv.y, acc[r].y);
                    acc[r].z = fmaf(q[r], xv.z, acc[r].z);
                    acc[r].w = fmaf(q[r], xv.w, acc[r].w);
                }
            }
        } else {
#pragma unroll 4
            for (int c = 0; c < C; ++c) {
                const float* rowc = xb + (size_t)c * NPTS;
                float4 xv = *reinterpret_cast<const float4*>(&rowc[m0]);
                float4 q0 = *reinterpret_cast<const float4*>(&xq[(size_t)c * NPTS]);
                float4 q1 = *reinterpret_cast<const float4*>(&xq[(size_t)c * NPTS + 4]);
                float q[8] = {q0.x, q0.y, q0.z, q0.w, q1.x, q1.y, q1.z, q1.w};
#pragma unroll
                for (int r = 0; r < 8; ++r) {
                    acc[r].x = fmaf(q[r], xv.x, acc[r].x);
                    acc[r].y = fmaf(q[r], xv.y, acc[r].y);
                    acc[r].z = fmaf(q[r], xv.z, acc[r].z);
                    acc[r].w = fmaf(q[r], xv.w, acc[r].w);
                }
            }
        }
        // store dist, XOR-swizzled: element m lives at m ^ (((m>>5)&7)<<2)
        {
            int p = m0 ^ (((m0 >> 5) & 7) << 2);
#pragma unroll
            for (int r = 0; r < 8; ++r) {
                float4 dv;
                dv.x = 2.f * acc[r].x - sn.x;
                dv.y = 2.f * acc[r].y - sn.y;
                dv.z = 2.f * acc[r].z - sn.z;
                dv.w = 2.f * acc[r].w - sn.w;
                *reinterpret_cast<float4*>(&dist[r][p]) = dv;
            }
        }
        __syncthreads();

        // ---- selection phase: wave w owns query row w; lane owns 32 contiguous cols
        float v[32];
        {
            const float* drow = &dist[w][32 * lane];
            int s = (lane & 7) << 2;
#pragma unroll
            for (int u = 0; u < 8; ++u) {
                float4 t = *reinterpret_cast<const float4*>(&drow[(4 * u) ^ s]);
                v[4 * u + 0] = t.x; v[4 * u + 1] = t.y;
                v[4 * u + 2] = t.z; v[4 * u + 3] = t.w;
            }
        }

        // group state: 4 groups of 8, track (max, argmax-with-smallest-index)
        float gm[4]; int gi[4];
#pragma unroll
        for (int g = 0; g < 4; ++g) {
            gm[g] = v[8 * g]; gi[g] = 8 * g;
#pragma unroll
            for (int i = 1; i < 8; ++i)
                if (v[8 * g + i] > gm[g]) { gm[g] = v[8 * g + i]; gi[g] = 8 * g + i; }
        }
        float lv = gm[0]; int lm = gi[0];
#pragma unroll
        for (int g = 1; g < 4; ++g) if (gm[g] > lv) { lv = gm[g]; lm = gi[g]; }

        int rbm = 0;

        for (int j = 0; j < KNN; ++j) {
            float gv = wave_max_bcast(lv);
            unsigned long long mk = __ballot(lv == gv);
            int winner = (int)__builtin_ctzll(mk);              // lowest lane = lowest index
            int wm = __builtin_amdgcn_readlane(lm, winner);     // uniform slot 0..31
            int bm = winner * 32 + wm;                          // global column
            rbm = (lane == j) ? bm : rbm;

            bool iswin = (lane == winner);
            int g = wm >> 3, ii = wm & 7;                       // uniform scalars
#pragma unroll
            for (int gq = 0; gq < 4; ++gq) {
                if (gq == g) {                                  // uniform branch
#pragma unroll
                    for (int i = 0; i < 8; ++i)
                        v[8 * gq + i] = (iswin && (ii == i)) ? -INFINITY : v[8 * gq + i];
                    float nm = v[8 * gq]; int ni = 8 * gq;
#pragma unroll
                    for (int i = 1; i < 8; ++i)
                        if (v[8 * gq + i] > nm) { nm = v[8 * gq + i]; ni = 8 * gq + i; }
                    gm[gq] = iswin ? nm : gm[gq];
                    gi[gq] = iswin ? ni : gi[gq];
                }
            }
            lv = gm[0]; lm = gi[0];
#pragma unroll
            for (int g2 = 1; g2 < 4; ++g2) if (gm[g2] > lv) { lv = gm[g2]; lm = gi[g2]; }
        }
        // transposed write: idxT[b][j][n]
        if (lane < KNN) idxT[((size_t)b * KNN + lane) * NPTS + n0 + w] = rbm;

        if (rg < 3) __syncthreads();   // protect dist before next group's overwrite
    }
}

// ---- Wa[c][o] = W[o][c]; Wd[c][o] = W[o][C+c] - W[o][c]
__global__ void prep_w_kernel(const float* __restrict__ W, int C, int O,
                              float* __restrict__ Wa, float* __restrict__ Wd) {
    int t = blockIdx.x * blockDim.x + threadIdx.x;
    if (t >= C * O) return;
    int c = t / O, o = t % O;
    float a = W[o * 2 * C + c];
    float d = W[o * 2 * C + C + c] - a;
    Wa[c * O + o] = a;
    Wd[c * O + o] = d;
}

// ---- y[b,o,m] = Wa@x_m ; base[b,off+o,n] = Wd@x_n + bias
__global__ __launch_bounds__(256) void edge_mm_kernel(const float* __restrict__ xin, long bstride,
                                                      int C, int O,
                                                      const float* __restrict__ Wa,
                                                      const float* __restrict__ Wd,
                                                      const float* __restrict__ bias,
                                                      float* __restrict__ y,
                                                      float* __restrict__ base, long base_bstride) {
    int m = blockIdx.x * 256 + threadIdx.x;
    int ngrp = O >> 3;
    int og = blockIdx.y % ngrp, b = blockIdx.y / ngrp;
    int o0 = og * 8;
    const float* xb = xin + (size_t)b * bstride + m;
    float a1[8], a2[8];
#pragma unroll
    for (int i = 0; i < 8; ++i) { a1[i] = 0.f; a2[i] = 0.f; }
#pragma unroll 2
    for (int c = 0; c < C; ++c) {
        float h = xb[(size_t)c * NPTS];
        const float* wa = Wa + c * O + o0;
        const float* wd = Wd + c * O + o0;
#pragma unroll
        for (int i = 0; i < 8; ++i) {
            a1[i] = fmaf(wa[i], h, a1[i]);
            a2[i] = fmaf(wd[i], h, a2[i]);
        }
    }
#pragma unroll
    for (int i = 0; i < 8; ++i) {
        y[((size_t)b * O + o0 + i) * NPTS + m] = a1[i];
        base[(size_t)b * base_bstride + (size_t)(o0 + i) * NPTS + m] = a2[i] + bias[o0 + i];
    }
}

// ---- feat[b,o0+i,n] = lrelu( max_j y[b,o0+i,idxT[b,j,n]] + base ), 8 channels/block.
// Grid 1D = (O/8)*2*NB: b = id&15 (XCD colocation), nc = (id>>4)&1, og = id>>5.
__global__ __launch_bounds__(256) void gather_max_kernel(const float* __restrict__ y, int O,
                                                         const int* __restrict__ idxT,
                                                         float* __restrict__ feat_slice,
                                                         long bstride) {
    __shared__ __align__(16) float yrow[8][NPTS];   // 64 KB
    int b  = blockIdx.x & 15;
    int nc = (blockIdx.x >> 4) & 1;
    int og = blockIdx.x >> 5;
    int o0 = og * 8;
    const float* ysrc = y + ((size_t)b * O + o0) * NPTS;
    for (int e = threadIdx.x; e < 8 * (NPTS / 4); e += 256) {
        int i = e >> 9;
        int m4 = e & 511;
        *reinterpret_cast<float4*>(&yrow[i][4 * m4]) =
            *reinterpret_cast<const float4*>(&ysrc[(size_t)i * NPTS + 4 * m4]);
    }
    __syncthreads();
    float* fs = feat_slice + (size_t)b * bstride + (size_t)o0 * NPTS;
    const int* ib = idxT + (size_t)b * KNN * NPTS + nc * (NPTS / 2);
    for (int s = 0; s < 4; ++s) {
        int n = threadIdx.x + 256 * s;
        int gn = nc * (NPTS / 2) + n;
        float mx[8];
#pragma unroll
        for (int i = 0; i < 8; ++i) mx[i] = -INFINITY;
#pragma unroll 4
        for (int j = 0; j < KNN; ++j) {
            int id = ib[(size_t)j * NPTS + n];
#pragma unroll
            for (int i = 0; i < 8; ++i) mx[i] = fmaxf(mx[i], yrow[i][id]);
        }
#pragma unroll
        for (int i = 0; i < 8; ++i) {
            float* fp = fs + (size_t)i * NPTS + gn;
            *fp = lrelu(mx[i] + *fp);
        }
    }
}

// ---- split Wf (fp32 [1024][512]) into packed bf16 hi/lo
__global__ void wf_split_kernel(const float* __restrict__ Wf,
                                unsigned* __restrict__ Wfh, unsigned* __restrict__ Wfl) {
    int t = blockIdx.x * 256 + threadIdx.x;   // pair index
    if (t >= 262144) return;
    unsigned h, l;
    split2(Wf[2 * t], Wf[2 * t + 1], h, l);
    Wfh[t] = h; Wfl[t] = l;
}

// ---- final GEMM via bf16 hi/lo split MFMA, with max-over-n epilogue
#define GP 40   // LDS pitch in bf16 elements (+8 pad: 2-way bank aliasing only)
__global__ __launch_bounds__(256) void final_gemm_mfma(
    const float* __restrict__ feat,
    const unsigned short* __restrict__ Wfh,
    const unsigned short* __restrict__ Wfl,
    float* __restrict__ pmax) {
    __shared__ __align__(16) unsigned short Ah[128 * GP];
    __shared__ __align__(16) unsigned short Al[128 * GP];
    __shared__ __align__(16) unsigned short Bh[128 * GP];
    __shared__ __align__(16) unsigned short Bl[128 * GP];

    int ot = blockIdx.x, nt = blockIdx.y, b = blockIdx.z;
    int o0 = ot * 128, n0 = nt * 128;
    int tid = threadIdx.x;
    int lane = tid & 63, w = tid >> 6;
    int wm = w & 1, wn = w >> 1;
    int l15 = lane & 15, q = lane >> 4;

    f32x4 acc[4][4];
#pragma unroll
    for (int mi = 0; mi < 4; ++mi)
#pragma unroll
        for (int ni = 0; ni < 4; ++ni) acc[mi][ni] = (f32x4)0.f;

    const float* fb = feat + (size_t)b * 512 * NPTS;
    int bn = tid & 127, kh = tid >> 7;

    for (int c0 = 0; c0 < 512; c0 += 32) {
#pragma unroll
        for (int p = 0; p < 2; ++p) {
            int e = p * 256 + tid;
            int r = e >> 2, qq = e & 3;
            size_t go = (size_t)(o0 + r) * 512 + c0 + qq * 8;
            *(uint4*)&Ah[r * GP + qq * 8] = *(const uint4*)(Wfh + go);
            *(uint4*)&Al[r * GP + qq * 8] = *(const uint4*)(Wfl + go);
        }
        {
            const float* src = fb + (size_t)(c0 + kh * 16) * NPTS + n0 + bn;
            float v[16];
#pragma unroll
            for (int j = 0; j < 16; ++j) v[j] = src[(size_t)j * NPTS];
            unsigned hw[8], lw[8];
#pragma unroll
            for (int p = 0; p < 8; ++p) split2(v[2 * p], v[2 * p + 1], hw[p], lw[p]);
            unsigned short* bh = &Bh[bn * GP + kh * 16];
            unsigned short* bl = &Bl[bn * GP + kh * 16];
            *(uint4*)(bh)     = make_uint4(hw[0], hw[1], hw[2], hw[3]);
            *(uint4*)(bh + 8) = make_uint4(hw[4], hw[5], hw[6], hw[7]);
            *(uint4*)(bl)     = make_uint4(lw[0], lw[1], lw[2], lw[3]);
            *(uint4*)(bl + 8) = make_uint4(lw[4], lw[5], lw[6], lw[7]);
        }
        __syncthreads();

        bf16x8 bhf[4], blf[4];
#pragma unroll
        for (int ni = 0; ni < 4; ++ni) {
            int row = wn * 64 + ni * 16 + l15;
            bhf[ni] = *(const bf16x8*)&Bh[row * GP + q * 8];
            blf[ni] = *(const bf16x8*)&Bl[row * GP + q * 8];
        }
#pragma unroll
        for (int mi = 0; mi < 4; ++mi) {
            int row = wm * 64 + mi * 16 + l15;
            bf16x8 ah = *(const bf16x8*)&Ah[row * GP + q * 8];
            bf16x8 al = *(const bf16x8*)&Al[row * GP + q * 8];
#pragma unroll
            for (int ni = 0; ni < 4; ++ni) {
                acc[mi][ni] = __builtin_amdgcn_mfma_f32_16x16x32_bf16(ah, bhf[ni], acc[mi][ni], 0, 0, 0);
                acc[mi][ni] = __builtin_amdgcn_mfma_f32_16x16x32_bf16(ah, blf[ni], acc[mi][ni], 0, 0, 0);
                acc[mi][ni] = __builtin_amdgcn_mfma_f32_16x16x32_bf16(al, bhf[ni], acc[mi][ni], 0, 0, 0);
            }
        }
        __syncthreads();
    }

    int slot = nt * 2 + wn;
#pragma unroll
    for (int mi = 0; mi < 4; ++mi) {
        float m4[4];
#pragma unroll
        for (int r = 0; r < 4; ++r) {
            float m = acc[mi][0][r];
            m = fmaxf(m, acc[mi][1][r]);
            m = fmaxf(m, acc[mi][2][r]);
            m = fmaxf(m, acc[mi][3][r]);
            m4[r] = m;
        }
#pragma unroll
        for (int off = 1; off < 16; off <<= 1) {
#pragma unroll
            for (int r = 0; r < 4; ++r)
                m4[r] = fmaxf(m4[r], __shfl_xor(m4[r], off, 16));
        }
        if (l15 == 0) {
            int mbase = o0 + wm * 64 + mi * 16 + q * 4;
#pragma unroll
            for (int r = 0; r < 4; ++r)
                pmax[((size_t)b * 1024 + mbase + r) * 32 + slot] = m4[r];
        }
    }
}

__global__ void final_reduce_kernel(const float* __restrict__ pmax,
                                    const float* __restrict__ bf,
                                    float* __restrict__ out) {
    int t = blockIdx.x * blockDim.x + threadIdx.x;   // b*1024+o
    if (t >= NB * 1024) return;
    const float* p = pmax + (size_t)t * 32;
    float m = p[0];
#pragma unroll
    for (int i = 1; i < 32; ++i) m = fmaxf(m, p[i]);
    out[t] = lrelu(m + bf[t & 1023]);
}

extern "C" void kernel_launch(void* const* d_in, const int* in_sizes, int n_in,
                              void* d_out, int out_size, void* d_ws, size_t ws_size,
                              hipStream_t stream) {
    const float* x  = (const float*)d_in[0];
    const float* W[4]  = {(const float*)d_in[1], (const float*)d_in[3],
                          (const float*)d_in[5], (const float*)d_in[7]};
    const float* bb[4] = {(const float*)d_in[2], (const float*)d_in[4],
                          (const float*)d_in[6], (const float*)d_in[8]};
    const float* Wf = (const float*)d_in[9];
    const float* bf = (const float*)d_in[10];
    float* out = (float*)d_out;

    float* ws   = (float*)d_ws;
    float* h0   = ws;                           // B*3*N      = 98304
    // (dead 32768-float region where sq used to live keeps offsets stable)
    int*   idxT = (int*)(ws + 98304 + 32768);   // B*20*N     = 655360 (transposed [b][j][n])
    float* y    = (float*)(idxT + 655360);      // B*256*N    = 8388608 (reused)
    float* feat = y + 8388608;                  // B*512*N    = 16777216
    float* Wa   = feat + 16777216 + 262144;     // 128*256    = 32768
    float* Wd   = Wa + 32768;                   // 128*256    = 32768

    // carved out of the dead y-region after layer 4:
    unsigned* Wfh = (unsigned*)y;                    // 262144 dwords
    unsigned* Wfl = (unsigned*)(y + 262144);         // 262144 dwords
    float*    pmax = y + 524288;                     // 16*1024*32 = 524288 floats

    transpose_kernel<<<128, 256, 0, stream>>>(x, h0);

    const int  Cs[4]   = {3, 64, 64, 128};
    const int  Os[4]   = {64, 64, 128, 256};
    const int  offs[4] = {0, 64, 128, 256};

    for (int l = 0; l < 4; ++l) {
        const float* in = (l == 0) ? h0 : feat + (size_t)offs[l - 1] * NPTS;
        long bstr = (l == 0) ? (long)3 * NPTS : (long)512 * NPTS;
        int C = Cs[l], O = Os[l];

        // 1D grid: 64 query-groups x 16 batches; b = id&15 -> XCD = b%8 colocation
        int kb = (NPTS / 32) * NB;   // 1024 blocks
        if (C == 3)       knn_kernel<3>  <<<kb, 512, 0, stream>>>(in, bstr, idxT);
        else if (C == 64) knn_kernel<64> <<<kb, 512, 0, stream>>>(in, bstr, idxT);
        else              knn_kernel<128><<<kb, 512, 0, stream>>>(in, bstr, idxT);

        prep_w_kernel<<<(C * O + 255) / 256, 256, 0, stream>>>(W[l], C, O, Wa, Wd);

        float* fslice = feat + (size_t)offs[l] * NPTS;
        edge_mm_kernel<<<dim3(NPTS / 256, NB * (O >> 3)), 256, 0, stream>>>(
            in, bstr, C, O, Wa, Wd, bb[l], y, fslice, (long)512 * NPTS);

        // 1D grid: (O/8) o-groups x 2 n-halves x 16 batches; b = id&15 colocation
        gather_max_kernel<<<(O / 8) * 2 * NB, 256, 0, stream>>>(
            y, O, idxT, fslice, (long)512 * NPTS);
    }

    wf_split_kernel<<<1024, 256, 0, stream>>>(Wf, Wfh, Wfl);
    final_gemm_mfma<<<dim3(8, 16, NB), 256, 0, stream>>>(
        feat, (const unsigned short*)Wfh, (const unsigned short*)Wfl, pmax);
    final_reduce_kernel<<<64, 256, 0, stream>>>(pmax, bf, out);
}